// Round 1
// baseline (3444.029 us; speedup 1.0000x reference)
//
#include <hip/hip_runtime.h>
#include <math.h>

#define NH   4096
#define KCAT 8192
#define TPTS 16
#define NBLK 256   // persistent kernel: 1 block per CU

typedef unsigned short ushort_t;

// ---------------------------------------------------------------------------
// Wave (64-lane) reductions
// ---------------------------------------------------------------------------
__device__ __forceinline__ float wave_reduce64(float s) {
#pragma unroll
    for (int off = 32; off > 0; off >>= 1)
        s += __shfl_down(s, off, 64);
    return s;
}

// butterfly: result replicated in all 64 lanes
__device__ __forceinline__ float wrx64(float s) {
#pragma unroll
    for (int off = 32; off > 0; off >>= 1)
        s += __shfl_xor(s, off, 64);
    return s;
}

// ---------------------------------------------------------------------------
// fp32 -> bf16 (RNE) packing, bf16x8 unpack
// ---------------------------------------------------------------------------
__device__ __forceinline__ unsigned f2bf_pack2(float lo, float hi) {
    unsigned ul = __float_as_uint(lo);
    unsigned uh = __float_as_uint(hi);
    ul = (ul + 0x7fffu + ((ul >> 16) & 1u)) >> 16;
    uh = (uh + 0x7fffu + ((uh >> 16) & 1u)) >> 16;
    return ul | (uh << 16);
}

__device__ __forceinline__ ushort_t bf16_1(float x) {
    unsigned u = __float_as_uint(x);
    return (ushort_t)((u + 0x7fffu + ((u >> 16) & 1u)) >> 16);
}

__device__ __forceinline__ void bf16x8_to_f32(uint4 w, float* f) {
    f[0] = __uint_as_float(w.x << 16); f[1] = __uint_as_float(w.x & 0xffff0000u);
    f[2] = __uint_as_float(w.y << 16); f[3] = __uint_as_float(w.y & 0xffff0000u);
    f[4] = __uint_as_float(w.z << 16); f[5] = __uint_as_float(w.z & 0xffff0000u);
    f[6] = __uint_as_float(w.w << 16); f[7] = __uint_as_float(w.w & 0xffff0000u);
}

// ===========================================================================
// PERSISTENT COOPERATIVE ODE KERNEL
// 256 blocks x 512 threads (1 block/CU, 8 waves). Wave w owns rows
// r0 = blockIdx*16 + 2w, r1 = r0+1 of BOTH W1 and W2, held as packed-bf16
// register arrays (4 x 32 VGPRs = 128 VGPRs). The 2-column (fwd/bwd) state
// vector travels through global fp32 (float2-interleaved) between matvecs,
// separated by a 2-level device-scope barrier; each block stages it into LDS.
// ===========================================================================

// ---- 2-level grid barrier (16 leaves x 16 blocks). bar: 1024 uints, zeroed.
__device__ __forceinline__ void grid_barrier(unsigned* bar) {
    __syncthreads();
    if (threadIdx.x == 0) {
        unsigned* leaf = bar + 32 * (blockIdx.x >> 4);
        unsigned* root = bar + 32 * 16;
        unsigned* gen  = bar + 32 * 17;
        unsigned g = __hip_atomic_load(gen, __ATOMIC_RELAXED, __HIP_MEMORY_SCOPE_AGENT);
        bool done = false;
        if (__hip_atomic_fetch_add(leaf, 1u, __ATOMIC_ACQ_REL, __HIP_MEMORY_SCOPE_AGENT) == 15u) {
            __hip_atomic_store(leaf, 0u, __ATOMIC_RELAXED, __HIP_MEMORY_SCOPE_AGENT);
            if (__hip_atomic_fetch_add(root, 1u, __ATOMIC_ACQ_REL, __HIP_MEMORY_SCOPE_AGENT) == 15u) {
                __hip_atomic_store(root, 0u, __ATOMIC_RELAXED, __HIP_MEMORY_SCOPE_AGENT);
                __hip_atomic_store(gen, g + 1u, __ATOMIC_RELEASE, __HIP_MEMORY_SCOPE_AGENT);
                done = true;
            }
        }
        if (!done) {
            while (__hip_atomic_load(gen, __ATOMIC_ACQUIRE, __HIP_MEMORY_SCOPE_AGENT) == g)
                __builtin_amdgcn_s_sleep(2);
        }
    }
    __syncthreads();
}

__global__ __launch_bounds__(64) void zero_bar(unsigned* bar) {
    for (int i = threadIdx.x; i < 1024; i += 64) bar[i] = 0;
}

// dot of this wave's 2 rows (packed regs WA/WB) against uS (both cols).
// lane l covers element pairs (2l+128k, 2l+1+128k), k=0..31.
#define MV_DOT(WA, WB)                                                        \
    {                                                                         \
        s00 = 0.f; s01 = 0.f; s10 = 0.f; s11 = 0.f;                           \
        _Pragma("unroll")                                                     \
        for (int k = 0; k < 32; ++k) {                                        \
            float4 uu = *(const float4*)&uS[4 * l + 256 * k];                 \
            float wA0 = __uint_as_float(WA[k] << 16);                         \
            float wA1 = __uint_as_float(WA[k] & 0xffff0000u);                 \
            float wB0 = __uint_as_float(WB[k] << 16);                         \
            float wB1 = __uint_as_float(WB[k] & 0xffff0000u);                 \
            s00 = fmaf(wA0, uu.x, s00); s01 = fmaf(wA0, uu.y, s01);           \
            s00 = fmaf(wA1, uu.z, s00); s01 = fmaf(wA1, uu.w, s01);           \
            s10 = fmaf(wB0, uu.x, s10); s11 = fmaf(wB0, uu.y, s11);           \
            s10 = fmaf(wB1, uu.z, s10); s11 = fmaf(wB1, uu.w, s11);           \
        }                                                                     \
        s00 = wrx64(s00); s01 = wrx64(s01);                                   \
        s10 = wrx64(s10); s11 = wrx64(s11);                                   \
    }

// stage 32 KB (4096 float2, col-interleaved) from global into uS
#define STAGE_U(SRCP)                                                         \
    {                                                                         \
        const float4* g4_ = (const float4*)(SRCP);                            \
        float4* d4_ = (float4*)uS;                                            \
        _Pragma("unroll")                                                     \
        for (int i_ = 0; i_ < 4; ++i_)                                        \
            d4_[t + 512 * i_] = g4_[t + 512 * i_];                            \
    }

__global__ __launch_bounds__(512, 2) void ode_persistent(
    const float* __restrict__ W1, const float* __restrict__ b1,
    const float* __restrict__ W2, const float* __restrict__ b2,
    const float* __restrict__ h_f, const float* __restrict__ h_b,
    const float* __restrict__ tf, const float* __restrict__ tb,
    float2* __restrict__ Ug2, float2* __restrict__ Vg2,
    unsigned* __restrict__ bar, float* __restrict__ Hg)
{
    __shared__ float uS[2 * NH];   // 32 KB: element j -> uS[2j]=col0, uS[2j+1]=col1
    const int t  = threadIdx.x;
    const int l  = t & 63;
    const int w  = t >> 6;
    const int r0 = blockIdx.x * 16 + 2 * w;
    const int r1 = r0 + 1;

    // ---- load this wave's 4 weight rows into packed-bf16 registers ----
    unsigned w1a[32], w1b[32], w2a[32], w2b[32];
    {
        const float2* p0 = (const float2*)(W1 + (size_t)r0 * NH);
        const float2* p1 = (const float2*)(W1 + (size_t)r1 * NH);
        const float2* q0 = (const float2*)(W2 + (size_t)r0 * NH);
        const float2* q1 = (const float2*)(W2 + (size_t)r1 * NH);
#pragma unroll
        for (int k = 0; k < 32; ++k) {
            int idx = l + 64 * k;
            float2 a = p0[idx];
            float2 b = p1[idx];
            float2 c = q0[idx];
            float2 d = q1[idx];
            w1a[k] = f2bf_pack2(a.x, a.y);
            w1b[k] = f2bf_pack2(b.x, b.y);
            w2a[k] = f2bf_pack2(c.x, c.y);
            w2b[k] = f2bf_pack2(d.x, d.y);
        }
    }

    // ---- initial u = h0 staged straight from inputs ----
    {
        const float4* hf4 = (const float4*)h_f;
        const float4* hb4 = (const float4*)h_b;
        float4* d4 = (float4*)uS;
#pragma unroll
        for (int i = 0; i < 2; ++i) {
            float4 a = hf4[t + 512 * i];
            float4 b = hb4[t + 512 * i];
            d4[2 * (t + 512 * i)]     = make_float4(a.x, b.x, a.y, b.y);
            d4[2 * (t + 512 * i) + 1] = make_float4(a.z, b.z, a.w, b.w);
        }
    }

    float H00 = h_f[r0], H01 = h_b[r0], H10 = h_f[r1], H11 = h_b[r1];
    const float bb10 = b1[r0], bb11 = b1[r1];
    const float bb20 = b2[r0], bb21 = b2[r1];
    float A00 = 0.f, A01 = 0.f, A10 = 0.f, A11 = 0.f;

    __syncthreads();

    for (int s = 0; s < TPTS - 1; ++s) {
        const float dt0 = tf[s + 1] - tf[s];
        const float dt1 = tb[s + 1] - tb[s];
        for (int st = 0; st < 4; ++st) {
            float s00, s01, s10, s11;

            // === mv1: v = tanh(W1 u + b1) ===
            MV_DOT(w1a, w1b);
            {
                float v00 = tanhf(s00 + bb10), v01 = tanhf(s01 + bb10);
                float v10 = tanhf(s10 + bb11), v11 = tanhf(s11 + bb11);
                if (l == 0) {
                    Vg2[r0] = make_float2(v00, v01);
                    Vg2[r1] = make_float2(v10, v11);
                }
            }
            grid_barrier(bar);
            STAGE_U(Vg2);
            __syncthreads();

            // === mv2: k = W2 v + b2; RK4 accumulate; publish next u ===
            MV_DOT(w2a, w2b);
            {
                float k00 = s00 + bb20, k01 = s01 + bb20;
                float k10 = s10 + bb21, k11 = s11 + bb21;
                float wgt = (st == 1 || st == 2) ? 2.f : 1.f;
                if (st == 0) { A00 = H00; A01 = H01; A10 = H10; A11 = H11; }
                A00 += wgt * (dt0 / 6.f) * k00;  A01 += wgt * (dt1 / 6.f) * k01;
                A10 += wgt * (dt0 / 6.f) * k10;  A11 += wgt * (dt1 / 6.f) * k11;
                float u00, u01, u10, u11;
                if (st == 3) {
                    H00 = A00; H01 = A01; H10 = A10; H11 = A11;
                    u00 = H00; u01 = H01; u10 = H10; u11 = H11;
                } else {
                    float cn = (st == 2) ? 1.f : 0.5f;
                    u00 = H00 + cn * dt0 * k00;  u01 = H01 + cn * dt1 * k01;
                    u10 = H10 + cn * dt0 * k10;  u11 = H11 + cn * dt1 * k11;
                }
                if (l == 0) {
                    Ug2[r0] = make_float2(u00, u01);
                    Ug2[r1] = make_float2(u10, u11);
                }
            }
            grid_barrier(bar);
            STAGE_U(Ug2);
            __syncthreads();
        }
    }

    // final h -> Hg for the GRU/head tail
    if (l == 0) {
        Hg[r0]      = H00;  Hg[NH + r0] = H01;
        Hg[r1]      = H10;  Hg[NH + r1] = H11;
    }
}

// ===========================================================================
// Fallback path kernels (previous best version, unchanged)
// ===========================================================================

__global__ __launch_bounds__(256) void cvt_bf16_kernel(const float* __restrict__ src,
                                                       ushort_t* __restrict__ dst, int n8) {
    int i = blockIdx.x * 256 + threadIdx.x;
    if (i < n8) {
        const float4* s4 = (const float4*)src;
        float4 a = s4[2 * i], b = s4[2 * i + 1];
        uint4 o;
        o.x = f2bf_pack2(a.x, a.y);
        o.y = f2bf_pack2(a.z, a.w);
        o.z = f2bf_pack2(b.x, b.y);
        o.w = f2bf_pack2(b.z, b.w);
        ((uint4*)dst)[i] = o;
    }
}

__global__ __launch_bounds__(256) void init_hu(const float* __restrict__ h_f,
                                               const float* __restrict__ h_b,
                                               float* __restrict__ H,
                                               ushort_t* __restrict__ Ubf) {
    int i = blockIdx.x * 256 + threadIdx.x;
    float a = h_f[i], b = h_b[i];
    H[i]       = a;  H[NH + i]   = b;
    Ubf[i]     = bf16_1(a);
    Ubf[NH + i] = bf16_1(b);
}

__global__ __launch_bounds__(512, 4) void ode_mv1(
    const ushort_t* __restrict__ W1b, const float* __restrict__ b1,
    const ushort_t* __restrict__ Ubf, ushort_t* __restrict__ Vbf)
{
    __shared__ uint4 uS[1024];
    const int t = threadIdx.x;
    {
        const uint4* U4 = (const uint4*)Ubf;
        uS[t]       = U4[t];
        uS[t + 512] = U4[t + 512];
    }
    __syncthreads();

    const int l   = t & 63;
    const int row = blockIdx.x * 8 + (t >> 6);
    const uint4* __restrict__ W4 = (const uint4*)(W1b + (size_t)row * NH);

    float s0 = 0.f, s1 = 0.f;
#pragma unroll
    for (int i = 0; i < 8; ++i) {
        int idx = l + 64 * i;
        uint4 wv = W4[idx];
        uint4 u0 = uS[idx];
        uint4 u1 = uS[512 + idx];
        float wf[8], a0[8], a1[8];
        bf16x8_to_f32(wv, wf);
        bf16x8_to_f32(u0, a0);
        bf16x8_to_f32(u1, a1);
#pragma unroll
        for (int k = 0; k < 8; ++k) {
            s0 += wf[k] * a0[k];
            s1 += wf[k] * a1[k];
        }
    }
    s0 = wave_reduce64(s0);
    s1 = wave_reduce64(s1);
    if (l == 0) {
        float bb = b1[row];
        Vbf[row]      = bf16_1(tanhf(s0 + bb));
        Vbf[NH + row] = bf16_1(tanhf(s1 + bb));
    }
}

__global__ __launch_bounds__(512, 4) void ode_mv2(
    const ushort_t* __restrict__ W2b, const float* __restrict__ b2,
    const ushort_t* __restrict__ Vbf,
    const float* __restrict__ tf, const float* __restrict__ tb, int sidx,
    float wgt, float cnext, int stage,
    float* __restrict__ H, float* __restrict__ ACC,
    ushort_t* __restrict__ Ubf)
{
    __shared__ uint4 vS[1024];
    const int t = threadIdx.x;
    {
        const uint4* V4 = (const uint4*)Vbf;
        vS[t]       = V4[t];
        vS[t + 512] = V4[t + 512];
    }
    __syncthreads();

    const int l   = t & 63;
    const int row = blockIdx.x * 8 + (t >> 6);
    const uint4* __restrict__ W4 = (const uint4*)(W2b + (size_t)row * NH);
    const float dt0 = tf[sidx + 1] - tf[sidx];
    const float dt1 = tb[sidx + 1] - tb[sidx];

    float s0 = 0.f, s1 = 0.f;
#pragma unroll
    for (int i = 0; i < 8; ++i) {
        int idx = l + 64 * i;
        uint4 wv = W4[idx];
        uint4 v0 = vS[idx];
        uint4 v1 = vS[512 + idx];
        float wf[8], a0[8], a1[8];
        bf16x8_to_f32(wv, wf);
        bf16x8_to_f32(v0, a0);
        bf16x8_to_f32(v1, a1);
#pragma unroll
        for (int k = 0; k < 8; ++k) {
            s0 += wf[k] * a0[k];
            s1 += wf[k] * a1[k];
        }
    }
    s0 = wave_reduce64(s0);
    s1 = wave_reduce64(s1);
    if (l == 0) {
        float bb = b2[row];
        float k0 = s0 + bb, k1 = s1 + bb;
        float base0 = (stage == 0) ? H[row]      : ACC[row];
        float base1 = (stage == 0) ? H[NH + row] : ACC[NH + row];
        float a0 = base0 + wgt * (dt0 / 6.f) * k0;
        float a1 = base1 + wgt * (dt1 / 6.f) * k1;
        ACC[row]      = a0;
        ACC[NH + row] = a1;
        if (stage == 3) {
            H[row]      = a0;
            H[NH + row] = a1;
            Ubf[row]      = bf16_1(a0);
            Ubf[NH + row] = bf16_1(a1);
        } else {
            Ubf[row]      = bf16_1(H[row]      + cnext * dt0 * k0);
            Ubf[NH + row] = bf16_1(H[NH + row] + cnext * dt1 * k1);
        }
    }
}

__global__ __launch_bounds__(256) void init_h_kernel(const float* __restrict__ h_f,
                                                     const float* __restrict__ h_b,
                                                     float* __restrict__ H) {
    int i = blockIdx.x * 256 + threadIdx.x;
    H[i]      = h_f[i];
    H[NH + i] = h_b[i];
}

__global__ __launch_bounds__(256) void rk4_mv1_f32(
    const float* __restrict__ W1, const float* __restrict__ b1,
    const float* __restrict__ H,  const float* __restrict__ Kv,
    const float* __restrict__ tf, const float* __restrict__ tb,
    int tidx, float coef, int useK,
    float* __restrict__ V)
{
    const int row  = blockIdx.x * 4 + (threadIdx.x >> 6);
    const int lane = threadIdx.x & 63;
    const float a0 = coef * (tf[tidx + 1] - tf[tidx]);
    const float a1 = coef * (tb[tidx + 1] - tb[tidx]);

    const float4* __restrict__ W4 = (const float4*)(W1 + (size_t)row * NH);
    const float4* __restrict__ x0 = (const float4*)(H);
    const float4* __restrict__ x1 = (const float4*)(H + NH);
    const float4* __restrict__ k0 = (const float4*)(Kv);
    const float4* __restrict__ k1 = (const float4*)(Kv + NH);

    float s0 = 0.f, s1 = 0.f;
    if (useK) {
#pragma unroll 8
        for (int i = 0; i < NH / 4 / 64; ++i) {
            int idx = lane + i * 64;
            float4 w  = W4[idx];
            float4 h0 = x0[idx], h1 = x1[idx];
            float4 p0 = k0[idx], p1 = k1[idx];
            s0 += w.x * (h0.x + a0 * p0.x) + w.y * (h0.y + a0 * p0.y)
                + w.z * (h0.z + a0 * p0.z) + w.w * (h0.w + a0 * p0.w);
            s1 += w.x * (h1.x + a1 * p1.x) + w.y * (h1.y + a1 * p1.y)
                + w.z * (h1.z + a1 * p1.z) + w.w * (h1.w + a1 * p1.w);
        }
    } else {
#pragma unroll 8
        for (int i = 0; i < NH / 4 / 64; ++i) {
            int idx = lane + i * 64;
            float4 w  = W4[idx];
            float4 h0 = x0[idx], h1 = x1[idx];
            s0 += w.x * h0.x + w.y * h0.y + w.z * h0.z + w.w * h0.w;
            s1 += w.x * h1.x + w.y * h1.y + w.z * h1.z + w.w * h1.w;
        }
    }
    s0 = wave_reduce64(s0);
    s1 = wave_reduce64(s1);
    if (lane == 0) {
        float bb = b1[row];
        V[row]      = tanhf(s0 + bb);
        V[NH + row] = tanhf(s1 + bb);
    }
}

__global__ __launch_bounds__(256) void rk4_mv2_f32(
    const float* __restrict__ W2, const float* __restrict__ b2,
    const float* __restrict__ V,
    const float* __restrict__ tf, const float* __restrict__ tb,
    int tidx, float wgt,
    const float* __restrict__ Hbase,
    float* __restrict__ Kout, float* __restrict__ ACC)
{
    const int row  = blockIdx.x * 4 + (threadIdx.x >> 6);
    const int lane = threadIdx.x & 63;

    const float4* __restrict__ W4 = (const float4*)(W2 + (size_t)row * NH);
    const float4* __restrict__ v0 = (const float4*)(V);
    const float4* __restrict__ v1 = (const float4*)(V + NH);

    float s0 = 0.f, s1 = 0.f;
#pragma unroll 8
    for (int i = 0; i < NH / 4 / 64; ++i) {
        int idx = lane + i * 64;
        float4 w = W4[idx];
        float4 a = v0[idx], b = v1[idx];
        s0 += w.x * a.x + w.y * a.y + w.z * a.z + w.w * a.w;
        s1 += w.x * b.x + w.y * b.y + w.z * b.z + w.w * b.w;
    }
    s0 = wave_reduce64(s0);
    s1 = wave_reduce64(s1);
    if (lane == 0) {
        float bb  = b2[row];
        float k0v = s0 + bb;
        float k1v = s1 + bb;
        Kout[row]      = k0v;
        Kout[NH + row] = k1v;
        const float dt0 = tf[tidx + 1] - tf[tidx];
        const float dt1 = tb[tidx + 1] - tb[tidx];
        ACC[row]      = Hbase[row]      + wgt * (dt0 / 6.f) * k0v;
        ACC[NH + row] = Hbase[NH + row] + wgt * (dt1 / 6.f) * k1v;
    }
}

// ---------------------------------------------------------------------------
// GRU / head kernels (fp32 weights; used 1-2x each)
// ---------------------------------------------------------------------------
__global__ __launch_bounds__(256) void build_xcat_kernel(
    const float* __restrict__ x_f, const float* __restrict__ x_b,
    const float* __restrict__ H,
    float* __restrict__ xcat1, float* __restrict__ xcat2)
{
    int i = blockIdx.x * 256 + threadIdx.x;
    float xf = x_f[i], xb = x_b[i];
    xcat1[i]               = xf;
    xcat2[i]               = xf;
    xcat1[KCAT + i]        = xb;
    xcat2[KCAT + i]        = xb;
    xcat1[NH + i]          = H[i];
    xcat1[KCAT + NH + i]   = H[NH + i];
}

__global__ __launch_bounds__(256) void gru_mv1(
    const float* __restrict__ Wi, const float* __restrict__ bi,
    const float* __restrict__ xcat1, const float* __restrict__ H,
    float* __restrict__ G, float* __restrict__ xcat2)
{
    const int row  = blockIdx.x * 4 + (threadIdx.x >> 6);
    const int lane = threadIdx.x & 63;

    const float4* __restrict__ W4 = (const float4*)(Wi + (size_t)row * KCAT);
    const float4* __restrict__ c0 = (const float4*)(xcat1);
    const float4* __restrict__ c1 = (const float4*)(xcat1 + KCAT);

    float s0 = 0.f, s1 = 0.f;
#pragma unroll 8
    for (int i = 0; i < KCAT / 4 / 64; ++i) {
        int idx = lane + i * 64;
        float4 w = W4[idx];
        float4 a = c0[idx], b = c1[idx];
        s0 += w.x * a.x + w.y * a.y + w.z * a.z + w.w * a.w;
        s1 += w.x * b.x + w.y * b.y + w.z * b.z + w.w * b.w;
    }
    s0 = wave_reduce64(s0);
    s1 = wave_reduce64(s1);
    if (lane == 0) {
        float bb = bi[row];
        float g0 = 1.f / (1.f + expf(-(s0 + bb)));
        float g1 = 1.f / (1.f + expf(-(s1 + bb)));
        G[row]      = g0;
        G[NH + row] = g1;
        xcat2[NH + row]        = g0 * H[row];
        xcat2[KCAT + NH + row] = g1 * H[NH + row];
    }
}

__global__ __launch_bounds__(256) void gru_mv2(
    const float* __restrict__ Wi, const float* __restrict__ bi,
    const float* __restrict__ xcat2, const float* __restrict__ H,
    const float* __restrict__ G,
    float* __restrict__ out, float* __restrict__ hcat)
{
    const int row  = blockIdx.x * 4 + (threadIdx.x >> 6);
    const int lane = threadIdx.x & 63;

    const float4* __restrict__ W4 = (const float4*)(Wi + (size_t)row * KCAT);
    const float4* __restrict__ c0 = (const float4*)(xcat2);
    const float4* __restrict__ c1 = (const float4*)(xcat2 + KCAT);

    float s0 = 0.f, s1 = 0.f;
#pragma unroll 8
    for (int i = 0; i < KCAT / 4 / 64; ++i) {
        int idx = lane + i * 64;
        float4 w = W4[idx];
        float4 a = c0[idx], b = c1[idx];
        s0 += w.x * a.x + w.y * a.y + w.z * a.z + w.w * a.w;
        s1 += w.x * b.x + w.y * b.y + w.z * b.z + w.w * b.w;
    }
    s0 = wave_reduce64(s0);
    s1 = wave_reduce64(s1);
    if (lane == 0) {
        float bb  = bi[row];
        float hh0 = tanhf(s0 + bb);
        float hh1 = tanhf(s1 + bb);
        float g0  = G[row], g1 = G[NH + row];
        float hf  = g0 * H[row]      + (1.f - g0) * hh0;
        float hb  = g1 * H[NH + row] + (1.f - g1) * hh1;
        out[NH + row]     = hf;
        out[2 * NH + row] = hb;
        hcat[row]      = hf;
        hcat[NH + row] = hb;
    }
}

__global__ __launch_bounds__(256) void h2o_mv(
    const float* __restrict__ W, const float* __restrict__ b,
    const float* __restrict__ hcat, float* __restrict__ out)
{
    const int row  = blockIdx.x * 4 + (threadIdx.x >> 6);
    const int lane = threadIdx.x & 63;

    const float4* __restrict__ W4 = (const float4*)(W + (size_t)row * KCAT);
    const float4* __restrict__ x4 = (const float4*)(hcat);

    float s = 0.f;
#pragma unroll 8
    for (int i = 0; i < KCAT / 4 / 64; ++i) {
        int idx = lane + i * 64;
        float4 w = W4[idx];
        float4 a = x4[idx];
        s += w.x * a.x + w.y * a.y + w.z * a.z + w.w * a.w;
    }
    s = wave_reduce64(s);
    if (lane == 0)
        out[row] = s + b[row];
}

// ---------------------------------------------------------------------------
extern "C" void kernel_launch(void* const* d_in, const int* in_sizes, int n_in,
                              void* d_out, int out_size, void* d_ws, size_t ws_size,
                              hipStream_t stream) {
    const float* x_f   = (const float*)d_in[0];
    const float* x_b   = (const float*)d_in[1];
    const float* h_f   = (const float*)d_in[2];
    const float* h_b   = (const float*)d_in[3];
    const float* t_f   = (const float*)d_in[4];
    const float* t_b   = (const float*)d_in[5];
    const float* i2h_W = (const float*)d_in[6];
    const float* i2h_b = (const float*)d_in[7];
    const float* h2o_W = (const float*)d_in[8];
    const float* h2o_b = (const float*)d_in[9];
    const float* f_W1  = (const float*)d_in[10];
    const float* f_b1  = (const float*)d_in[11];
    const float* f_W2  = (const float*)d_in[12];
    const float* f_b2  = (const float*)d_in[13];
    float* out = (float*)d_out;

    // ---- workspace layout (all offsets 16B-aligned) ----
    float* ws    = (float*)d_ws;
    float* Hg    = ws;                  // 2*NH fp32
    float* ACCg  = Hg    + 2 * NH;      // 2*NH fp32
    float* Vg32  = ACCg  + 2 * NH;      // 2*NH fp32 (fallback V)
    float* Kg32  = Vg32  + 2 * NH;      // 2*NH fp32 (fallback K)
    float* xcat1 = Kg32  + 2 * NH;      // 2*KCAT
    float* xcat2 = xcat1 + 2 * KCAT;    // 2*KCAT
    float* G     = xcat2 + 2 * KCAT;    // 2*NH
    float* hcat  = G     + 2 * NH;      // KCAT
    float* fend  = hcat  + KCAT;
    ushort_t* Ubf = (ushort_t*)fend;            // 2*NH bf16 (16 KB)
    ushort_t* Vbf = Ubf + 2 * NH;               // 2*NH bf16 (16 KB)
    ushort_t* W1b = Vbf + 2 * NH;               // NH*NH bf16 (32 MB, fallback only)
    ushort_t* W2b = W1b + (size_t)NH * NH;      // NH*NH bf16 (32 MB, fallback only)
    size_t need = (size_t)((char*)(W2b + (size_t)NH * NH) - (char*)d_ws);
    const bool fast = ws_size >= need;

    // coop-path buffers alias the (unused-in-coop) W1b region
    float2*   Ug2  = (float2*)W1b;                 // 4096 float2 (32 KB)
    float2*   Vg2  = Ug2 + NH;                     // 4096 float2 (32 KB)
    unsigned* barp = (unsigned*)(Vg2 + NH);        // 1024 uints (4 KB)
    size_t coop_need = (size_t)((char*)(barp + 1024) - (char*)d_ws);

    dim3 blk(256);

    bool ode_done = false;
    if (ws_size >= coop_need) {
        zero_bar<<<1, 64, 0, stream>>>(barp);
        void* kargs[] = { (void*)&f_W1, (void*)&f_b1, (void*)&f_W2, (void*)&f_b2,
                          (void*)&h_f,  (void*)&h_b,  (void*)&t_f,  (void*)&t_b,
                          (void*)&Ug2,  (void*)&Vg2,  (void*)&barp, (void*)&Hg };
        hipError_t e = hipLaunchCooperativeKernel(ode_persistent, dim3(NBLK), dim3(512),
                                                  kargs, 0, stream);
        ode_done = (e == hipSuccess);
    }

    if (!ode_done) {
        if (fast) {
            const int n8 = NH * NH / 8;
            cvt_bf16_kernel<<<n8 / 256, blk, 0, stream>>>(f_W1, W1b, n8);
            cvt_bf16_kernel<<<n8 / 256, blk, 0, stream>>>(f_W2, W2b, n8);
            init_hu<<<NH / 256, blk, 0, stream>>>(h_f, h_b, Hg, Ubf);

            for (int s = 0; s < TPTS - 1; ++s) {
                ode_mv1<<<512, 512, 0, stream>>>(W1b, f_b1, Ubf, Vbf);
                ode_mv2<<<512, 512, 0, stream>>>(W2b, f_b2, Vbf, t_f, t_b, s,
                                                 1.f, 0.5f, 0, Hg, ACCg, Ubf);
                ode_mv1<<<512, 512, 0, stream>>>(W1b, f_b1, Ubf, Vbf);
                ode_mv2<<<512, 512, 0, stream>>>(W2b, f_b2, Vbf, t_f, t_b, s,
                                                 2.f, 0.5f, 1, Hg, ACCg, Ubf);
                ode_mv1<<<512, 512, 0, stream>>>(W1b, f_b1, Ubf, Vbf);
                ode_mv2<<<512, 512, 0, stream>>>(W2b, f_b2, Vbf, t_f, t_b, s,
                                                 2.f, 1.0f, 2, Hg, ACCg, Ubf);
                ode_mv1<<<512, 512, 0, stream>>>(W1b, f_b1, Ubf, Vbf);
                ode_mv2<<<512, 512, 0, stream>>>(W2b, f_b2, Vbf, t_f, t_b, s,
                                                 1.f, 0.0f, 3, Hg, ACCg, Ubf);
            }
        } else {
            const int mv_grid = NH / 4;
            init_h_kernel<<<NH / 256, blk, 0, stream>>>(h_f, h_b, Hg);
            float* H   = Hg;
            float* ACC = ACCg;
            for (int s = 0; s < TPTS - 1; ++s) {
                rk4_mv1_f32<<<mv_grid, blk, 0, stream>>>(f_W1, f_b1, H, Kg32, t_f, t_b, s, 0.0f, 0, Vg32);
                rk4_mv2_f32<<<mv_grid, blk, 0, stream>>>(f_W2, f_b2, Vg32, t_f, t_b, s, 1.0f, H,   Kg32, ACC);
                rk4_mv1_f32<<<mv_grid, blk, 0, stream>>>(f_W1, f_b1, H, Kg32, t_f, t_b, s, 0.5f, 1, Vg32);
                rk4_mv2_f32<<<mv_grid, blk, 0, stream>>>(f_W2, f_b2, Vg32, t_f, t_b, s, 2.0f, ACC, Kg32, ACC);
                rk4_mv1_f32<<<mv_grid, blk, 0, stream>>>(f_W1, f_b1, H, Kg32, t_f, t_b, s, 0.5f, 1, Vg32);
                rk4_mv2_f32<<<mv_grid, blk, 0, stream>>>(f_W2, f_b2, Vg32, t_f, t_b, s, 2.0f, ACC, Kg32, ACC);
                rk4_mv1_f32<<<mv_grid, blk, 0, stream>>>(f_W1, f_b1, H, Kg32, t_f, t_b, s, 1.0f, 1, Vg32);
                rk4_mv2_f32<<<mv_grid, blk, 0, stream>>>(f_W2, f_b2, Vg32, t_f, t_b, s, 1.0f, ACC, Kg32, ACC);
                float* tmp = H; H = ACC; ACC = tmp;
            }
            if (H != Hg) {
                hipMemcpyAsync(Hg, H, 2 * NH * sizeof(float), hipMemcpyDeviceToDevice, stream);
            }
        }
    }

    const int mv_grid = NH / 4;
    build_xcat_kernel<<<NH / 256, blk, 0, stream>>>(x_f, x_b, Hg, xcat1, xcat2);
    gru_mv1<<<mv_grid, blk, 0, stream>>>(i2h_W, i2h_b, xcat1, Hg, G, xcat2);
    gru_mv2<<<mv_grid, blk, 0, stream>>>(i2h_W, i2h_b, xcat2, Hg, G, out, hcat);
    h2o_mv <<<mv_grid, blk, 0, stream>>>(h2o_W, h2o_b, hcat, out);
}